// Round 7
// baseline (462.682 us; speedup 1.0000x reference)
//
#include <hip/hip_runtime.h>
#include <math.h>
#include <stdint.h>

#define B_ 64
#define J_ 512
#define D_ 1024

typedef __attribute__((ext_vector_type(8))) short short8;
typedef __attribute__((ext_vector_type(4))) float f32x4;

#define GLOBAL_AS __attribute__((address_space(1)))
#define LDS_AS    __attribute__((address_space(3)))

__device__ __forceinline__ void async16(const void* g, void* l) {
    __builtin_amdgcn_global_load_lds((const GLOBAL_AS uint32_t*)g,
                                     (LDS_AS uint32_t*)l, 16, 0, 0);
}

// tanh(x) = 1 - 2/(1+e^{2x}); saturates correctly for |x| large.
__device__ __forceinline__ float fast_tanh(float x) {
    return 1.0f - 2.0f / (1.0f + __expf(2.0f * x));
}

// fp32 -> bf16 round-to-nearest-even
__device__ __forceinline__ uint32_t f2bf(float f) {
    uint32_t u = __builtin_bit_cast(uint32_t, f);
    u += 0x7fffu + ((u >> 16) & 1u);
    return u >> 16;
}
__device__ __forceinline__ uint32_t pack2(float lo, float hi) {
    return f2bf(lo) | (f2bf(hi) << 16);
}

// ---------------------------------------------------------------------------
// prep: blocks [0,256)   -> W1[k][n] fp32 -> W1t[n][k] bf16 (64x64 tiles)
//       blocks [256,320) -> zero pooled (+cnt in block 256)
//       blocks [320, +16384) -> X fp32 -> Xb bf16 (8 elems/thread, vectorized)
// ---------------------------------------------------------------------------
__global__ __launch_bounds__(256) void prep_kernel(
    const float* __restrict__ x, const float* __restrict__ W1,
    unsigned short* __restrict__ Xb, unsigned short* __restrict__ W1t,
    float* __restrict__ pooled, unsigned int* __restrict__ cnt)
{
    const int bx = blockIdx.x;
    const int tx = threadIdx.x;

    if (bx < 256) {
        // --- W1 transpose-cast, 64x64 tile ---
        __shared__ float t[64][65];
        const int k0 = (bx >> 4) * 64;
        const int n0 = (bx & 15) * 64;
        const int kr = tx >> 4;            // 0..15
        const int c4 = (tx & 15) << 2;     // 0..60
        #pragma unroll
        for (int j = 0; j < 4; ++j) {
            const float4 v = *reinterpret_cast<const float4*>(
                &W1[(size_t)(k0 + kr + 16 * j) * D_ + n0 + c4]);
            t[kr + 16 * j][c4 + 0] = v.x;
            t[kr + 16 * j][c4 + 1] = v.y;
            t[kr + 16 * j][c4 + 2] = v.z;
            t[kr + 16 * j][c4 + 3] = v.w;
        }
        __syncthreads();
        const int nl = tx >> 3;            // 0..31
        const int k8 = (tx & 7) << 3;      // 0..56
        #pragma unroll
        for (int s = 0; s < 2; ++s) {
            const int n = nl + 32 * s;
            uint4 o;
            o.x = pack2(t[k8 + 0][n], t[k8 + 1][n]);
            o.y = pack2(t[k8 + 2][n], t[k8 + 3][n]);
            o.z = pack2(t[k8 + 4][n], t[k8 + 5][n]);
            o.w = pack2(t[k8 + 6][n], t[k8 + 7][n]);
            *reinterpret_cast<uint4*>(&W1t[(size_t)(n0 + n) * D_ + k0 + k8]) = o;
        }
    } else if (bx < 320) {
        // --- zero pooled (64 blocks x 256 threads x float4 = 256 KB) + cnt ---
        const int i = ((bx - 256) * 256 + tx) * 4;
        *reinterpret_cast<float4*>(pooled + i) = make_float4(0.f, 0.f, 0.f, 0.f);
        if (bx == 256 && tx < B_) cnt[tx] = 0u;
    } else {
        // --- X cast ---
        const size_t i = ((size_t)(bx - 320) * 256 + tx) * 8;
        const float4 v0 = *reinterpret_cast<const float4*>(x + i);
        const float4 v1 = *reinterpret_cast<const float4*>(x + i + 4);
        uint4 o;
        o.x = pack2(v0.x, v0.y);
        o.y = pack2(v0.z, v0.w);
        o.z = pack2(v1.x, v1.y);
        o.w = pack2(v1.z, v1.w);
        *reinterpret_cast<uint4*>(Xb + i) = o;
    }
}

// ---------------------------------------------------------------------------
// gemm+score (round-2 proven structure: 117 us, MfmaUtil 24%, occ 45%).
// Block tile 64(M) x 256(N-chunk) x 4 sweeps, BK=64; 8 waves, wave tile 64x32.
// A and B both staged via width-16 global_load_lds (no sync vmem in k-loop).
// Fused tanh/W2 fold -> sigmoid/mask -> atomic pooling (unnormalized;
// normalization commutes) -> last-block-per-batch inline finalize.
// ---------------------------------------------------------------------------
__global__ __launch_bounds__(512, 4) void gemm_score_kernel(
    const unsigned short* __restrict__ Xb, const unsigned short* __restrict__ W1t,
    const float* __restrict__ x,
    const float* __restrict__ b1, const float* __restrict__ W2,
    const float* __restrict__ b2, const float* __restrict__ mask,
    const float* __restrict__ W3, const float* __restrict__ b3,
    float* __restrict__ out, float* __restrict__ val_ws,
    float* __restrict__ pooled, unsigned int* __restrict__ cnt)
{
    __shared__ __align__(16) unsigned short ldsA[64 * 64];    // [m][k], swizzled
    __shared__ __align__(16) unsigned short ldsB[256 * 64];   // [n][k], swizzled
    __shared__ float b1s[D_], w2s[D_];
    __shared__ float pv_part[8][64];   // also sred[512] in inline finalize
    __shared__ float vrow[64];
    __shared__ int lastflag;

    const int tid  = threadIdx.x;
    const int wave = tid >> 6;
    const int l    = tid & 63;
    const int wn   = wave;            // wave grid 1(M) x 8(N)
    const int l15  = l & 15;
    const int kgrp = l >> 4;
    const int l7   = l & 7;
    const int r0   = blockIdx.x * 64; // rows of this block (within one batch)
    const int bb   = r0 >> 9;         // batch index

    b1s[tid] = b1[tid]; b1s[tid + 512] = b1[tid + 512];
    w2s[tid] = W2[tid]; w2s[tid + 512] = W2[tid + 512];

    // A tile 64x64 bf16 = 8 KB = 1 async16/thread
    const int arow = tid >> 3;
    const int achv = ((tid & 7) ^ (arow & 7)) << 3;   // swizzled k-chunk
    const unsigned short* gA = Xb + (size_t)(r0 + arow) * D_ + achv;
    unsigned short* lA = ldsA + (wave << 9);
    // B tile 256x64 bf16 = 32 KB = 4 async16/thread
    const unsigned short* gB[4];
    unsigned short* lB[4];
    #pragma unroll
    for (int t = 0; t < 4; ++t) {
        const int f = tid + t * 512;
        const int row = f >> 3;
        const int ch = ((f & 7) ^ (row & 7)) << 3;
        gB[t] = W1t + (size_t)row * D_ + ch;
        lB[t] = ldsB + t * 4096 + (wave << 9);
    }

    // fragment LDS offsets (ushort units), swizzle-consistent (validated r2)
    int aoff[4][2], boff[2][2];
    #pragma unroll
    for (int mi = 0; mi < 4; ++mi)
        #pragma unroll
        for (int ks = 0; ks < 2; ++ks)
            aoff[mi][ks] = (mi * 16 + l15) * 64 + (((ks * 4 + kgrp) ^ l7) << 3);
    #pragma unroll
    for (int ni = 0; ni < 2; ++ni)
        #pragma unroll
        for (int ks = 0; ks < 2; ++ks)
            boff[ni][ks] = (wn * 32 + ni * 16 + l15) * 64 +
                           (((ks * 4 + kgrp) ^ l7) << 3);

    float pv[4][4];
    #pragma unroll
    for (int mi = 0; mi < 4; ++mi)
        #pragma unroll
        for (int r = 0; r < 4; ++r) pv[mi][r] = 0.f;

    for (int n0 = 0; n0 < 4; ++n0) {
        f32x4 acc[4][2];
        #pragma unroll
        for (int mi = 0; mi < 4; ++mi)
            #pragma unroll
            for (int ni = 0; ni < 2; ++ni)
                acc[mi][ni] = (f32x4){0.f, 0.f, 0.f, 0.f};

        const size_t bofs = (size_t)n0 * 256 * D_;
        for (int k0 = 0; k0 < D_; k0 += 64) {
            async16(gA + k0, lA);
            #pragma unroll
            for (int t = 0; t < 4; ++t) async16(gB[t] + bofs + k0, lB[t]);
            __syncthreads();
            #pragma unroll
            for (int ks = 0; ks < 2; ++ks) {
                const short8 a0 = *reinterpret_cast<const short8*>(ldsA + aoff[0][ks]);
                const short8 a1 = *reinterpret_cast<const short8*>(ldsA + aoff[1][ks]);
                const short8 a2 = *reinterpret_cast<const short8*>(ldsA + aoff[2][ks]);
                const short8 a3 = *reinterpret_cast<const short8*>(ldsA + aoff[3][ks]);
                const short8 b0 = *reinterpret_cast<const short8*>(ldsB + boff[0][ks]);
                const short8 b1f = *reinterpret_cast<const short8*>(ldsB + boff[1][ks]);
                acc[0][0] = __builtin_amdgcn_mfma_f32_16x16x32_bf16(a0, b0,  acc[0][0], 0, 0, 0);
                acc[1][0] = __builtin_amdgcn_mfma_f32_16x16x32_bf16(a1, b0,  acc[1][0], 0, 0, 0);
                acc[2][0] = __builtin_amdgcn_mfma_f32_16x16x32_bf16(a2, b0,  acc[2][0], 0, 0, 0);
                acc[3][0] = __builtin_amdgcn_mfma_f32_16x16x32_bf16(a3, b0,  acc[3][0], 0, 0, 0);
                acc[0][1] = __builtin_amdgcn_mfma_f32_16x16x32_bf16(a0, b1f, acc[0][1], 0, 0, 0);
                acc[1][1] = __builtin_amdgcn_mfma_f32_16x16x32_bf16(a1, b1f, acc[1][1], 0, 0, 0);
                acc[2][1] = __builtin_amdgcn_mfma_f32_16x16x32_bf16(a2, b1f, acc[2][1], 0, 0, 0);
                acc[3][1] = __builtin_amdgcn_mfma_f32_16x16x32_bf16(a3, b1f, acc[3][1], 0, 0, 0);
            }
            __syncthreads();
        }

        // fold this 256-col n-chunk of h into pv (h never materialized)
        #pragma unroll
        for (int ni = 0; ni < 2; ++ni) {
            const int col = n0 * 256 + wn * 32 + ni * 16 + l15;
            const float b1v = b1s[col];
            const float w2v = w2s[col];
            #pragma unroll
            for (int mi = 0; mi < 4; ++mi)
                #pragma unroll
                for (int r = 0; r < 4; ++r) {
                    const float h = fast_tanh(acc[mi][ni][r] + b1v);
                    pv[mi][r] = fmaf(h, w2v, pv[mi][r]);
                }
        }
    }

    // reduce pv over the 16 col-lanes (C/D layout: row = kgrp*4+r, col = l15)
    #pragma unroll
    for (int mi = 0; mi < 4; ++mi)
        #pragma unroll
        for (int r = 0; r < 4; ++r) {
            float s = pv[mi][r];
            s += __shfl_xor(s, 1);
            s += __shfl_xor(s, 2);
            s += __shfl_xor(s, 4);
            s += __shfl_xor(s, 8);
            if (l15 == 0) pv_part[wn][mi * 16 + kgrp * 4 + r] = s;
        }
    __syncthreads();
    if (tid < 64) {
        float s = b2[0];
        #pragma unroll
        for (int w = 0; w < 8; ++w) s += pv_part[w][tid];
        const float sg = 1.0f / (1.0f + __expf(-s));
        const float v = sg * mask[r0 + tid];
        val_ws[r0 + tid] = v;
        vrow[tid] = v;
    }
    __syncthreads();

    // unnormalized pooled: pooled[bb][k] += sum_rows x[r][k]*val[r] (fp32 x)
    {
        const int kc = tid << 1;
        float a0 = 0.f, a1 = 0.f;
        for (int row = 0; row < 64; ++row) {
            const float v = vrow[row];
            const float2 xv = *reinterpret_cast<const float2*>(
                x + (size_t)(r0 + row) * D_ + kc);
            a0 = fmaf(xv.x, v, a0);
            a1 = fmaf(xv.y, v, a1);
        }
        atomicAdd(&pooled[bb * D_ + kc], a0);
        atomicAdd(&pooled[bb * D_ + kc + 1], a1);
    }

    // ---- inline finalize: last of the batch's 8 blocks does it (proven r6) ----
    __threadfence();                       // release our val/pooled writes
    __syncthreads();
    if (tid == 0) {
        const unsigned int old = atomicAdd(&cnt[bb], 1u);
        lastflag = (old == 7u) ? 1 : 0;
    }
    __syncthreads();
    if (!lastflag) return;
    __threadfence();                       // acquire the other 7 blocks' writes

    {
        float* sred = &pv_part[0][0];      // 512 floats, pv_part is dead
        const int b = bb;

        const float v = val_ws[b * J_ + tid];
        sred[tid] = v;
        __syncthreads();
        for (int s = 256; s > 0; s >>= 1) {
            if (tid < s) sred[tid] += sred[tid + s];
            __syncthreads();
        }
        const float inv = 1.0f / sred[0];

        out[192 + b * J_ + tid] = v * inv;

        const int k = tid << 1;
        const float p0 = pooled[b * D_ + k] * inv;
        const float p1 = pooled[b * D_ + k + 1] * inv;
        float acc3[3];
        #pragma unroll
        for (int o = 0; o < 3; ++o)
            acc3[o] = fmaf(p0, W3[k * 3 + o], p1 * W3[(k + 1) * 3 + o]);
        #pragma unroll
        for (int o = 0; o < 3; ++o) {
            __syncthreads();
            sred[tid] = acc3[o];
            __syncthreads();
            for (int s = 256; s > 0; s >>= 1) {
                if (tid < s) sred[tid] += sred[tid + s];
                __syncthreads();
            }
            if (tid == 0) out[b * 3 + o] = sred[0] + b3[o];
        }
    }
}

extern "C" void kernel_launch(void* const* d_in, const int* in_sizes, int n_in,
                              void* d_out, int out_size, void* d_ws, size_t ws_size,
                              hipStream_t stream) {
    const float* x    = (const float*)d_in[0];
    const float* mask = (const float*)d_in[1];
    const float* W1   = (const float*)d_in[2];
    const float* b1   = (const float*)d_in[3];
    const float* W2   = (const float*)d_in[4];
    const float* b2   = (const float*)d_in[5];
    const float* W3   = (const float*)d_in[6];
    const float* b3   = (const float*)d_in[7];
    float* out = (float*)d_out;

    const size_t XB_BYTES  = (size_t)B_ * J_ * D_ * 2;   // 67,108,864
    const size_t W1T_BYTES = (size_t)D_ * D_ * 2;        //  2,097,152
    const size_t VAL_BYTES = (size_t)B_ * J_ * 4;        //    131,072
    const size_t PL_BYTES  = (size_t)B_ * D_ * 4;        //    262,144

    unsigned short* Xb  = (unsigned short*)d_ws;
    unsigned short* W1t = (unsigned short*)((char*)d_ws + XB_BYTES);
    float* val_ws = (float*)((char*)d_ws + XB_BYTES + W1T_BYTES);
    float* pooled = (float*)((char*)d_ws + XB_BYTES + W1T_BYTES + VAL_BYTES);
    unsigned int* cnt = (unsigned int*)((char*)d_ws + XB_BYTES + W1T_BYTES +
                                        VAL_BYTES + PL_BYTES);

    prep_kernel<<<320 + (B_ * J_ * D_) / (256 * 8), 256, 0, stream>>>(
        x, W1, Xb, W1t, pooled, cnt);
    gemm_score_kernel<<<512, 512, 0, stream>>>(Xb, W1t, x, b1, W2, b2, mask,
                                               W3, b3, out, val_ws, pooled, cnt);
}